// Round 5
// baseline (624.865 us; speedup 1.0000x reference)
//
#include <hip/hip_runtime.h>
#include <stdint.h>

typedef __bf16 bf16_t;
typedef __bf16 bf16x8 __attribute__((ext_vector_type(8)));
typedef __bf16 bf16x4 __attribute__((ext_vector_type(4)));
typedef float f32x4 __attribute__((ext_vector_type(4)));

// Async global->LDS, 16B per lane (wave-uniform base + lane*16).
#define GLOAD16(gp, lp)                                                        \
    __builtin_amdgcn_global_load_lds(                                          \
        (const __attribute__((address_space(1))) void*)(gp),                   \
        (__attribute__((address_space(3))) void*)(lp), 16, 0, 0)

#define MFMA16(a, b, c) __builtin_amdgcn_mfma_f32_16x16x32_bf16(a, b, c, 0, 0, 0)

#define SB() __builtin_amdgcn_sched_barrier(0)
#define BAR() asm volatile("s_barrier" ::: "memory")
#define LGKM0() asm volatile("s_waitcnt lgkmcnt(0)" ::: "memory")
#define VMW(n) asm volatile("s_waitcnt vmcnt(" #n ")" ::: "memory")

#define PH_PRE()                                                               \
    do {                                                                       \
        SB();                                                                  \
        BAR();                                                                 \
        LGKM0();                                                               \
        SB();                                                                  \
        __builtin_amdgcn_s_setprio(1);                                         \
    } while (0)
#define PH_POST()                                                              \
    do {                                                                       \
        __builtin_amdgcn_s_setprio(0);                                         \
        SB();                                                                  \
        BAR();                                                                 \
    } while (0)

// 16 independent MFMAs: 4 m-frags x 4 n-frags at ONE k-half -> no RAW
// adjacency on accumulators (R1's clusters had dependent k-pairs adjacent:
// matrix-pipe stalls; R0/R4 separate them and score 54-58% vs R1's 43%).
#define CL16(aa, bb, mo)                                                       \
    do {                                                                       \
        _Pragma("unroll") for (int mi_ = 0; mi_ < 4; ++mi_) {                  \
            _Pragma("unroll") for (int nj_ = 0; nj_ < 4; ++nj_) {              \
                acc[(mo) + mi_][nj_] =                                         \
                    MFMA16(aa[mi_], bb[nj_], acc[(mo) + mi_][nj_]);            \
            }                                                                  \
        }                                                                      \
    } while (0)

// BK=64 LDS tiles: row = 64 bf16 = 128 B = 32 banks; chunk c of row r lives
// in slot c ^ (r&7) (pre-swizzled global source, linear LDS dest). Readers
// XOR the same way -> 2-way (free) on ds_read_b128.

// ---------------------------------------------------------------------------
// All fp32 -> bf16 conversions in ONE launch (7 segments).
// ---------------------------------------------------------------------------
__global__ __launch_bounds__(256) void cvt_all_kernel(
    const float* __restrict__ x, const float* __restrict__ Wgu,
    const float* __restrict__ Bgu, const float* __restrict__ Wd,
    const float* __restrict__ Bd, const float* __restrict__ Agu,
    const float* __restrict__ Ad, bf16_t* __restrict__ X1,
    bf16_t* __restrict__ W1, bf16_t* __restrict__ W2,
    bf16_t* __restrict__ Abf, bf16_t* __restrict__ Adbf) {
    int b = blockIdx.x;
    const float* src;
    bf16_t* dst;
    int cshift, cmask, ldd, coff, lb;
    if (b < 16384) {
        src = x; dst = X1; cshift = 11; cmask = 2047; ldd = 2112; coff = 0; lb = b;
    } else if (b < 32768) {
        src = Wgu; dst = W1; cshift = 11; cmask = 2047; ldd = 2112; coff = 0; lb = b - 16384;
    } else if (b < 33280) {
        src = Bgu; dst = W1; cshift = 6; cmask = 63; ldd = 2112; coff = 2048; lb = b - 32768;
    } else if (b < 41472) {
        src = Wd; dst = W2; cshift = 12; cmask = 4095; ldd = 4160; coff = 0; lb = b - 33280;
    } else if (b < 41600) {
        src = Bd; dst = W2; cshift = 6; cmask = 63; ldd = 4160; coff = 4096; lb = b - 41472;
    } else if (b < 41728) {
        src = Agu; dst = Abf; cshift = 11; cmask = 2047; ldd = 2048; coff = 0; lb = b - 41600;
    } else {
        src = Ad; dst = Adbf; cshift = 12; cmask = 4095; ldd = 4096; coff = 0; lb = b - 41728;
    }
    int idx = (lb * 256 + threadIdx.x) << 2;
    int r = idx >> cshift;
    int c = idx & cmask;
    float4 v = *(const float4*)(src + idx);
    bf16x4 o = {(bf16_t)v.x, (bf16_t)v.y, (bf16_t)v.z, (bf16_t)v.w};
    *(bf16x4*)(dst + (size_t)r * ldd + coff + c) = o;
}

// ---------------------------------------------------------------------------
// LoRA GEMM: t = 0.25 * (A[M x K] @ Bw[64 x K]^T) -> dst cols [coff,coff+64).
// ---------------------------------------------------------------------------
__global__ __launch_bounds__(256) void lora_kernel(const bf16_t* __restrict__ A,
                                                   int lda,
                                                   const bf16_t* __restrict__ Bw,
                                                   int K, bf16_t* __restrict__ dst,
                                                   int ldd, int coff) {
    __shared__ __align__(16) bf16_t As[64 * 64];
    __shared__ __align__(16) bf16_t Bs[64 * 64];
    const int t = threadIdx.x;
    const int m0 = blockIdx.x * 64;
    const int lane = t & 63, w = t >> 6;
    const int ln15 = lane & 15, q = lane >> 4;

    const int lrow = t >> 3;
    const int lchunk = (t & 7) ^ (lrow & 7);
    const bf16_t* gaL = A + (size_t)(m0 + lrow) * lda + lchunk * 8;
    const bf16_t* gbL = Bw + (size_t)lrow * K + lchunk * 8;
    bf16_t* lA = As + t * 8;
    bf16_t* lB = Bs + t * 8;

    const f32x4 z = {0.f, 0.f, 0.f, 0.f};
    f32x4 acc[4];
#pragma unroll
    for (int j = 0; j < 4; ++j) acc[j] = z;

    int aoffs[2], boffs[2][4];
#pragma unroll
    for (int s = 0; s < 2; ++s) {
        int rowa = w * 16 + ln15;
        aoffs[s] = rowa * 64 + (((q + 4 * s) ^ (rowa & 7)) << 3);
#pragma unroll
        for (int j = 0; j < 4; ++j) {
            int rowb = j * 16 + ln15;
            boffs[s][j] = rowb * 64 + (((q + 4 * s) ^ (rowb & 7)) << 3);
        }
    }

    for (int kt = 0; kt < K; kt += 64) {
        GLOAD16(gaL, lA);
        GLOAD16(gaL + (size_t)32 * lda, lA + 32 * 64);
        GLOAD16(gbL, lB);
        GLOAD16(gbL + (size_t)32 * K, lB + 32 * 64);
        __syncthreads();
#pragma unroll
        for (int s = 0; s < 2; ++s) {
            bf16x8 av = *(const bf16x8*)(As + aoffs[s]);
#pragma unroll
            for (int j = 0; j < 4; ++j) {
                bf16x8 bv = *(const bf16x8*)(Bs + boffs[s][j]);
                acc[j] = MFMA16(av, bv, acc[j]);
            }
        }
        __syncthreads();
        gaL += 64;
        gbL += 64;
    }

#pragma unroll
    for (int j = 0; j < 4; ++j)
#pragma unroll
        for (int rg = 0; rg < 4; ++rg) {
            int m = m0 + w * 16 + q * 4 + rg;
            dst[(size_t)m * ldd + coff + j * 16 + ln15] = (bf16_t)(acc[j][rg] * 0.25f);
        }
}

// ---------------------------------------------------------------------------
// 256x256 4-phase core, v2 (k-separated clusters + balanced reads).
// 512 thr = 8 waves (2M x 4N), per-wave 128x64 out, acc[8][4].
// LDS 128 KiB: As0@0, As1@16384, Bs0@32768, Bs1@49152 (elements).
// Per K-tile g (buf = g&1), 4 phases:
//   p1: read aL(s0) 4 + bv(s0) 4; stage Blo(g+1)->nxt; vmcnt(4);
//       barrier; lgkm0; MFMA m0-3 x n0-3 x k0
//   p2: read aH(s0) 4;            stage Bhi(g+1)->nxt; MFMA m4-7 x k0
//   p3: read aL(s1) 4 + bv(s1) 4; stage A1(g+1)->nxt;  MFMA m0-3 x k1
//   p4: read aH(s1) 4;            stage A0(g+2)->cur; vmcnt(4); MFMA m4-7 x k1
// Staging safety: each stage target's last reads were issued >=1 barrier
// earlier and completed at that phase's lgkm0 (A0 read p1/p3 -> restaged p4;
// A1 read p2/p4 -> restaged next-tile p3; B read p1/p3 -> restaged
// next-tile p1/p2). vmcnt(4) at p1 retires A1(g) (needed p2); at p4 retires
// A0(g+1),Blo(g+1),Bhi(g+1) (needed next p1); leaves 4 loads in flight.
// Tail: kt clamped to last tile (harmless identical/unused re-stages) so
// counts stay uniform.
// ---------------------------------------------------------------------------
template <int LDA_, int LDB_, int NT_>
__device__ __forceinline__ void gemm4p_core(const bf16_t* __restrict__ gA,
                                            const bf16_t* __restrict__ gB0,
                                            const bf16_t* __restrict__ gB2,
                                            bf16_t* smem, const int t,
                                            const int offA0, const int offA1,
                                            const int offB0, const int offB1,
                                            f32x4 (&acc)[8][4]) {
    constexpr int KLAST = (NT_ - 1) * 64;
    auto stgA0 = [&](int kt, bf16_t* d) {  // A rows {0-63,128-191}
        GLOAD16(gA + kt, d + t * 8);
        GLOAD16(gA + (size_t)128 * LDA_ + kt, d + 128 * 64 + t * 8);
    };
    auto stgA1 = [&](int kt, bf16_t* d) {  // A rows {64-127,192-255}
        GLOAD16(gA + (size_t)64 * LDA_ + kt, d + 64 * 64 + t * 8);
        GLOAD16(gA + (size_t)192 * LDA_ + kt, d + 192 * 64 + t * 8);
    };
    auto stgBlo = [&](int kt, bf16_t* d) {  // B rows 0-127
        GLOAD16(gB0 + kt, d + t * 8);
        GLOAD16(gB0 + (size_t)64 * LDB_ + kt, d + 64 * 64 + t * 8);
    };
    auto stgBhi = [&](int kt, bf16_t* d) {  // B rows 128-255
        GLOAD16(gB2 + kt, d + 128 * 64 + t * 8);
        GLOAD16(gB2 + (size_t)64 * LDB_ + kt, d + 192 * 64 + t * 8);
    };

    bf16x8 aL[4], aH[4], bv[4];

    // Prologue: A0(0),Blo(0),Bhi(0) retired; A1(0),A0(1) in flight.
    stgA0(0, smem);
    stgBlo(0, smem + 32768);
    stgBhi(0, smem + 32768);
    stgA1(0, smem);
    stgA0(64 < KLAST ? 64 : KLAST, smem + 16384);
    VMW(4);
    BAR();

    for (int g = 0; g < NT_; ++g) {
        bf16_t* const Asc = smem + ((g & 1) << 14);
        bf16_t* const Bsc = Asc + 32768;
        bf16_t* const Asn = smem + (((g & 1) ^ 1) << 14);
        bf16_t* const Bsn = Asn + 32768;
        int k1 = (g + 1) << 6;
        if (k1 > KLAST) k1 = KLAST;
        int k2 = (g + 2) << 6;
        if (k2 > KLAST) k2 = KLAST;

        // ---- p1: m0-3 x k0 ----
#pragma unroll
        for (int i = 0; i < 4; ++i) aL[i] = *(const bf16x8*)(Asc + offA0 + i * 1024);
#pragma unroll
        for (int j = 0; j < 4; ++j) bv[j] = *(const bf16x8*)(Bsc + offB0 + j * 1024);
        stgBlo(k1, Bsn);
        VMW(4);
        PH_PRE();
        CL16(aL, bv, 0);
        PH_POST();

        // ---- p2: m4-7 x k0 ----
#pragma unroll
        for (int i = 0; i < 4; ++i) aH[i] = *(const bf16x8*)(Asc + offA0 + (4 + i) * 1024);
        stgBhi(k1, Bsn);
        PH_PRE();
        CL16(aH, bv, 4);
        PH_POST();

        // ---- p3: m0-3 x k1 ----
#pragma unroll
        for (int i = 0; i < 4; ++i) aL[i] = *(const bf16x8*)(Asc + offA1 + i * 1024);
#pragma unroll
        for (int j = 0; j < 4; ++j) bv[j] = *(const bf16x8*)(Bsc + offB1 + j * 1024);
        stgA1(k1, Asn);
        PH_PRE();
        CL16(aL, bv, 0);
        PH_POST();

        // ---- p4: m4-7 x k1 ----
#pragma unroll
        for (int i = 0; i < 4; ++i) aH[i] = *(const bf16x8*)(Asc + offA1 + (4 + i) * 1024);
        stgA0(k2, Asc);
        VMW(4);
        PH_PRE();
        CL16(aH, bv, 4);
        PH_POST();
    }
    VMW(0);
}

// Epilogue LDS park swizzle (R2, measured 0 conflicts).
__device__ __forceinline__ int eswz(int row, int col) {
    return col ^ (((row >> 2) & 1) << 4) ^ (((row >> 3) & 3) << 2);
}

// ---------------------------------------------------------------------------
// GEMM1 (fused gate_up + SwiGLU): X1[8192x2112] @ [gate|up]^T.
// B-tile rows 0-127 = gate cols n0.., rows 128-255 = up (W rows 4096+n0..).
// Waves wc<2 hold gate, wc>=2 up; SwiGLU combined through LDS epilogue.
// ---------------------------------------------------------------------------
__global__ __launch_bounds__(512, 2) void gemm1_8p_kernel(
    const bf16_t* __restrict__ X, const bf16_t* __restrict__ Wc,
    bf16_t* __restrict__ X2) {
    __shared__ __align__(16) bf16_t smem[65536];  // 128 KiB
    const int t = threadIdx.x;
    const int lane = t & 63, wid = t >> 6;
    const int wr = wid >> 2, wc = wid & 3;
    const int ln15 = lane & 15, q = lane >> 4;
    const int n0 = blockIdx.x * 128;
    const int m0 = blockIdx.y * 256;

    const int sw = ln15 & 7;
    const int offA0 = (wr * 128 + ln15) * 64 + ((q ^ sw) << 3);
    const int offA1 = (wr * 128 + ln15) * 64 + (((q + 4) ^ sw) << 3);
    const int offB0 = (wc * 64 + ln15) * 64 + ((q ^ sw) << 3);
    const int offB1 = (wc * 64 + ln15) * 64 + (((q + 4) ^ sw) << 3);

    const int rr = t >> 3;
    const int lch = (t & 7) ^ (rr & 7);
    const bf16_t* gA = X + (size_t)(m0 + rr) * 2112 + lch * 8;
    const bf16_t* gB0 = Wc + (size_t)(n0 + rr) * 2112 + lch * 8;          // gate
    const bf16_t* gB2 = Wc + (size_t)(4096 + n0 + rr) * 2112 + lch * 8;   // up

    f32x4 acc[8][4];
    const f32x4 z = {0.f, 0.f, 0.f, 0.f};
#pragma unroll
    for (int i = 0; i < 8; ++i)
#pragma unroll
        for (int j = 0; j < 4; ++j) acc[i][j] = z;

    gemm4p_core<2112, 2112, 33>(gA, gB0, gB2, smem, t, offA0, offA1, offB0,
                                offB1, acc);

    // Epilogue: up waves park acc in LDS (256x128 f32, bank-swizzled), gate
    // waves read matching up value and apply SwiGLU.
    __syncthreads();
    float* fs = (float*)smem;
    if (wc >= 2) {
#pragma unroll
        for (int mi = 0; mi < 8; ++mi)
#pragma unroll
            for (int nj = 0; nj < 4; ++nj)
#pragma unroll
                for (int rg = 0; rg < 4; ++rg) {
                    int row = wr * 128 + mi * 16 + q * 4 + rg;
                    int col = (wc - 2) * 64 + nj * 16 + ln15;
                    fs[row * 128 + eswz(row, col)] = acc[mi][nj][rg];
                }
    }
    __syncthreads();
    if (wc < 2) {
#pragma unroll
        for (int mi = 0; mi < 8; ++mi)
#pragma unroll
            for (int nj = 0; nj < 4; ++nj)
#pragma unroll
                for (int rg = 0; rg < 4; ++rg) {
                    int row = wr * 128 + mi * 16 + q * 4 + rg;
                    int col = wc * 64 + nj * 16 + ln15;
                    float gv = acc[mi][nj][rg];
                    float uv = fs[row * 128 + eswz(row, col)];
                    float h = uv * gv / (1.f + __expf(-gv));  // up * silu(gate)
                    X2[(size_t)(m0 + row) * 4160 + (n0 + col)] = (bf16_t)h;
                }
    }
}

// ---------------------------------------------------------------------------
// GEMM2: out = X2[8192x4160] @ Wdc[2048x4160]^T, fp32 out.
// grid (8, 32) = 256 blocks = exactly one round at 1 block/CU.
// ---------------------------------------------------------------------------
__global__ __launch_bounds__(512, 2) void gemm2_8p_kernel(
    const bf16_t* __restrict__ X2, const bf16_t* __restrict__ Wdc,
    float* __restrict__ out) {
    __shared__ __align__(16) bf16_t smem[65536];  // 128 KiB
    const int t = threadIdx.x;
    const int lane = t & 63, wid = t >> 6;
    const int wr = wid >> 2, wc = wid & 3;
    const int ln15 = lane & 15, q = lane >> 4;
    const int n0 = blockIdx.x * 256;
    const int m0 = blockIdx.y * 256;

    const int sw = ln15 & 7;
    const int offA0 = (wr * 128 + ln15) * 64 + ((q ^ sw) << 3);
    const int offA1 = (wr * 128 + ln15) * 64 + (((q + 4) ^ sw) << 3);
    const int offB0 = (wc * 64 + ln15) * 64 + ((q ^ sw) << 3);
    const int offB1 = (wc * 64 + ln15) * 64 + (((q + 4) ^ sw) << 3);

    const int rr = t >> 3;
    const int lch = (t & 7) ^ (rr & 7);
    const bf16_t* gA = X2 + (size_t)(m0 + rr) * 4160 + lch * 8;
    const bf16_t* gB0 = Wdc + (size_t)(n0 + rr) * 4160 + lch * 8;
    const bf16_t* gB2 = Wdc + (size_t)(n0 + 128 + rr) * 4160 + lch * 8;

    f32x4 acc[8][4];
    const f32x4 z = {0.f, 0.f, 0.f, 0.f};
#pragma unroll
    for (int i = 0; i < 8; ++i)
#pragma unroll
        for (int j = 0; j < 4; ++j) acc[i][j] = z;

    gemm4p_core<4160, 4160, 65>(gA, gB0, gB2, smem, t, offA0, offA1, offB0,
                                offB1, acc);

#pragma unroll
    for (int mi = 0; mi < 8; ++mi)
#pragma unroll
        for (int nj = 0; nj < 4; ++nj)
#pragma unroll
            for (int rg = 0; rg < 4; ++rg) {
                int row = wr * 128 + mi * 16 + q * 4 + rg;
                int col = wc * 64 + nj * 16 + ln15;
                out[(size_t)(m0 + row) * 2048 + (n0 + col)] = acc[mi][nj][rg];
            }
}

// ---------------------------------------------------------------------------
// Workspace layout (bytes):
//   X1   @ 0         : 8192 x 2112 bf16   [x | 0.25*x@A_gu^T]
//   W1   @ 34603008  : 8192 x 2112 bf16   [W_gu | B_gu]
//   X2   @ 69206016  : 8192 x 4160 bf16   [h | 0.25*h@A_d^T]
//   W2   @ 137363456 : 2048 x 4160 bf16   [W_d | B_d]
//   Abf  @ 154402816 : 64 x 2048 bf16
//   Adbf @ 154664960 : 64 x 4096 bf16
// ---------------------------------------------------------------------------
extern "C" void kernel_launch(void* const* d_in, const int* in_sizes, int n_in,
                              void* d_out, int out_size, void* d_ws, size_t ws_size,
                              hipStream_t stream) {
    const float* x = (const float*)d_in[0];
    const float* Wgu = (const float*)d_in[1];
    const float* Agu = (const float*)d_in[2];
    const float* Bgu = (const float*)d_in[3];
    const float* Wd = (const float*)d_in[4];
    const float* Ad = (const float*)d_in[5];
    const float* Bd = (const float*)d_in[6];
    float* out = (float*)d_out;

    char* ws = (char*)d_ws;
    bf16_t* X1 = (bf16_t*)(ws);
    bf16_t* W1 = (bf16_t*)(ws + 34603008);
    bf16_t* X2 = (bf16_t*)(ws + 69206016);
    bf16_t* W2 = (bf16_t*)(ws + 137363456);
    bf16_t* Abf = (bf16_t*)(ws + 154402816);
    bf16_t* Adbf = (bf16_t*)(ws + 154664960);

    // all fp32 -> bf16 conversions, single launch
    cvt_all_kernel<<<41984, 256, 0, stream>>>(x, Wgu, Bgu, Wd, Bd, Agu, Ad,
                                              X1, W1, W2, Abf, Adbf);

    // t1 = 0.25 * x @ A_gu^T  -> X1 cols [2048,2112)
    lora_kernel<<<128, 256, 0, stream>>>(X1, 2112, Abf, 2048, X1, 2112, 2048);
    // fused gate_up GEMM + SwiGLU -> X2 cols [0,4096)   (4-phase core v2)
    gemm1_8p_kernel<<<dim3(32, 32), 512, 0, stream>>>(X1, W1, X2);
    // t2 = 0.25 * h @ A_d^T -> X2 cols [4096,4160)
    lora_kernel<<<128, 256, 0, stream>>>(X2, 4160, Adbf, 4096, X2, 4160, 4096);
    // out = X2 @ [W_d|B_d]^T   (4-phase core v2)
    gemm2_8p_kernel<<<dim3(8, 32), 512, 0, stream>>>(X2, W2, out);
}

// Round 6
// 621.998 us; speedup vs baseline: 1.0046x; 1.0046x over previous
//
#include <hip/hip_runtime.h>
#include <stdint.h>

typedef __bf16 bf16_t;
typedef __bf16 bf16x8 __attribute__((ext_vector_type(8)));
typedef __bf16 bf16x4 __attribute__((ext_vector_type(4)));
typedef float f32x4 __attribute__((ext_vector_type(4)));

// Async global->LDS, 16B per lane (wave-uniform base + lane*16).
#define GLOAD16(gp, lp)                                                        \
    __builtin_amdgcn_global_load_lds(                                          \
        (const __attribute__((address_space(1))) void*)(gp),                   \
        (__attribute__((address_space(3))) void*)(lp), 16, 0, 0)

#define MFMA16(a, b, c) __builtin_amdgcn_mfma_f32_16x16x32_bf16(a, b, c, 0, 0, 0)

#define SB() __builtin_amdgcn_sched_barrier(0)
#define BAR() asm volatile("s_barrier" ::: "memory")
#define LGKM0() asm volatile("s_waitcnt lgkmcnt(0)" ::: "memory")
#define VMW(n) asm volatile("s_waitcnt vmcnt(" #n ")" ::: "memory")

#define PH_PRE()                                                               \
    do {                                                                       \
        SB();                                                                  \
        BAR();                                                                 \
        LGKM0();                                                               \
        SB();                                                                  \
        __builtin_amdgcn_s_setprio(1);                                         \
    } while (0)
#define PH_POST()                                                              \
    do {                                                                       \
        __builtin_amdgcn_s_setprio(0);                                         \
        SB();                                                                  \
        BAR();                                                                 \
    } while (0)

// 16 independent MFMAs: 4 m-frags x 4 n-frags at ONE k-half -> no RAW
// adjacency on accumulators.
#define CL16(aa, bb, mo)                                                       \
    do {                                                                       \
        _Pragma("unroll") for (int mi_ = 0; mi_ < 4; ++mi_) {                  \
            _Pragma("unroll") for (int nj_ = 0; nj_ < 4; ++nj_) {              \
                acc[(mo) + mi_][nj_] =                                         \
                    MFMA16(aa[mi_], bb[nj_], acc[(mo) + mi_][nj_]);            \
            }                                                                  \
        }                                                                      \
    } while (0)

// BK=64 LDS tiles: row = 64 bf16 = 128 B = 32 banks; chunk c of row r lives
// in slot c ^ (r&7) (pre-swizzled global source, linear LDS dest). Readers
// XOR the same way -> 2-way (free) on ds_read_b128.

// ---------------------------------------------------------------------------
// All fp32 -> bf16 conversions in ONE launch (7 segments).
// ---------------------------------------------------------------------------
__global__ __launch_bounds__(256) void cvt_all_kernel(
    const float* __restrict__ x, const float* __restrict__ Wgu,
    const float* __restrict__ Bgu, const float* __restrict__ Wd,
    const float* __restrict__ Bd, const float* __restrict__ Agu,
    const float* __restrict__ Ad, bf16_t* __restrict__ X1,
    bf16_t* __restrict__ W1, bf16_t* __restrict__ W2,
    bf16_t* __restrict__ Abf, bf16_t* __restrict__ Adbf) {
    int b = blockIdx.x;
    const float* src;
    bf16_t* dst;
    int cshift, cmask, ldd, coff, lb;
    if (b < 16384) {
        src = x; dst = X1; cshift = 11; cmask = 2047; ldd = 2112; coff = 0; lb = b;
    } else if (b < 32768) {
        src = Wgu; dst = W1; cshift = 11; cmask = 2047; ldd = 2112; coff = 0; lb = b - 16384;
    } else if (b < 33280) {
        src = Bgu; dst = W1; cshift = 6; cmask = 63; ldd = 2112; coff = 2048; lb = b - 32768;
    } else if (b < 41472) {
        src = Wd; dst = W2; cshift = 12; cmask = 4095; ldd = 4160; coff = 0; lb = b - 33280;
    } else if (b < 41600) {
        src = Bd; dst = W2; cshift = 6; cmask = 63; ldd = 4160; coff = 4096; lb = b - 41472;
    } else if (b < 41728) {
        src = Agu; dst = Abf; cshift = 11; cmask = 2047; ldd = 2048; coff = 0; lb = b - 41600;
    } else {
        src = Ad; dst = Adbf; cshift = 12; cmask = 4095; ldd = 4096; coff = 0; lb = b - 41728;
    }
    int idx = (lb * 256 + threadIdx.x) << 2;
    int r = idx >> cshift;
    int c = idx & cmask;
    float4 v = *(const float4*)(src + idx);
    bf16x4 o = {(bf16_t)v.x, (bf16_t)v.y, (bf16_t)v.z, (bf16_t)v.w};
    *(bf16x4*)(dst + (size_t)r * ldd + coff + c) = o;
}

// ---------------------------------------------------------------------------
// LoRA GEMM: t = 0.25 * (A[M x K] @ Bw[64 x K]^T) -> dst cols [coff,coff+64).
// ---------------------------------------------------------------------------
__global__ __launch_bounds__(256) void lora_kernel(const bf16_t* __restrict__ A,
                                                   int lda,
                                                   const bf16_t* __restrict__ Bw,
                                                   int K, bf16_t* __restrict__ dst,
                                                   int ldd, int coff) {
    __shared__ __align__(16) bf16_t As[64 * 64];
    __shared__ __align__(16) bf16_t Bs[64 * 64];
    const int t = threadIdx.x;
    const int m0 = blockIdx.x * 64;
    const int lane = t & 63, w = t >> 6;
    const int ln15 = lane & 15, q = lane >> 4;

    const int lrow = t >> 3;
    const int lchunk = (t & 7) ^ (lrow & 7);
    const bf16_t* gaL = A + (size_t)(m0 + lrow) * lda + lchunk * 8;
    const bf16_t* gbL = Bw + (size_t)lrow * K + lchunk * 8;
    bf16_t* lA = As + t * 8;
    bf16_t* lB = Bs + t * 8;

    const f32x4 z = {0.f, 0.f, 0.f, 0.f};
    f32x4 acc[4];
#pragma unroll
    for (int j = 0; j < 4; ++j) acc[j] = z;

    int aoffs[2], boffs[2][4];
#pragma unroll
    for (int s = 0; s < 2; ++s) {
        int rowa = w * 16 + ln15;
        aoffs[s] = rowa * 64 + (((q + 4 * s) ^ (rowa & 7)) << 3);
#pragma unroll
        for (int j = 0; j < 4; ++j) {
            int rowb = j * 16 + ln15;
            boffs[s][j] = rowb * 64 + (((q + 4 * s) ^ (rowb & 7)) << 3);
        }
    }

    for (int kt = 0; kt < K; kt += 64) {
        GLOAD16(gaL, lA);
        GLOAD16(gaL + (size_t)32 * lda, lA + 32 * 64);
        GLOAD16(gbL, lB);
        GLOAD16(gbL + (size_t)32 * K, lB + 32 * 64);
        __syncthreads();
#pragma unroll
        for (int s = 0; s < 2; ++s) {
            bf16x8 av = *(const bf16x8*)(As + aoffs[s]);
#pragma unroll
            for (int j = 0; j < 4; ++j) {
                bf16x8 bv = *(const bf16x8*)(Bs + boffs[s][j]);
                acc[j] = MFMA16(av, bv, acc[j]);
            }
        }
        __syncthreads();
        gaL += 64;
        gbL += 64;
    }

#pragma unroll
    for (int j = 0; j < 4; ++j)
#pragma unroll
        for (int rg = 0; rg < 4; ++rg) {
            int m = m0 + w * 16 + q * 4 + rg;
            dst[(size_t)m * ldd + coff + j * 16 + ln15] = (bf16_t)(acc[j][rg] * 0.25f);
        }
}

// ---------------------------------------------------------------------------
// GEMM1 (ROUND-4 version, best measured 247 us, FETCH 203 MB):
// per-wave tile 128x64. Block: 256 thr = 4 waves (2M x 2N). Tile M=256,
// out-cols 64 (gate+up). acc[8][4] (nj 0-1 gate, 2-3 up); SwiGLU in-register.
// LDS: A 256x64 + B 128x64 = 48 KB -> 2 blk/CU. Plain 2-barrier loop.
// ---------------------------------------------------------------------------
__global__ __launch_bounds__(256, 2) void gemm1_kernel(const bf16_t* __restrict__ X,
                                                       const bf16_t* __restrict__ Wc,
                                                       bf16_t* __restrict__ X2) {
    constexpr int LDA = 2112, LDW = 2112, LDX2 = 4160, K = 2112;
    __shared__ __align__(16) bf16_t As[256 * 64];  // 32 KB
    __shared__ __align__(16) bf16_t Bs[128 * 64];  // 16 KB
    const int t = threadIdx.x;
    const int n0 = blockIdx.x * 64;
    const int m0 = blockIdx.y * 256;
    const int lane = t & 63, w = t >> 6, wr = w >> 1, wc = w & 1;
    const int ln15 = lane & 15, q = lane >> 4;

    const int lrow = t >> 3;
    const int lchunk = (t & 7) ^ (lrow & 7);
    const bf16_t* gaL = X + (size_t)(m0 + lrow) * LDA + lchunk * 8;
    const bf16_t* gbgL = Wc + (size_t)(n0 + lrow) * LDW + lchunk * 8;          // gate
    const bf16_t* gbuL = Wc + (size_t)(4096 + n0 + lrow) * LDW + lchunk * 8;   // up
    bf16_t* lA = As + t * 8;
    bf16_t* lB = Bs + t * 8;

    const f32x4 z = {0.f, 0.f, 0.f, 0.f};
    f32x4 acc[8][4];  // [mi][nj]: nj 0-1 gate, 2-3 up
#pragma unroll
    for (int i = 0; i < 8; ++i)
#pragma unroll
        for (int j = 0; j < 4; ++j) acc[i][j] = z;

    // row&7 == ln15&7 for every fragment (frag strides are multiples of 16),
    // so each s-half needs only one base offset; frag steps are +1024.
    const int sw7 = ln15 & 7;
    const int arow = wr * 128 + ln15;
    const int aoff0 = arow * 64 + ((q ^ sw7) << 3);
    const int aoff1 = arow * 64 + (((q + 4) ^ sw7) << 3);
    const int brow = wc * 32 + ln15;
    const int boff0 = brow * 64 + ((q ^ sw7) << 3);
    const int boff1 = brow * 64 + (((q + 4) ^ sw7) << 3);

    for (int kt = 0; kt < K; kt += 64) {
        GLOAD16(gaL, lA);
        GLOAD16(gaL + (size_t)32 * LDA, lA + 32 * 64);
        GLOAD16(gaL + (size_t)64 * LDA, lA + 64 * 64);
        GLOAD16(gaL + (size_t)96 * LDA, lA + 96 * 64);
        GLOAD16(gaL + (size_t)128 * LDA, lA + 128 * 64);
        GLOAD16(gaL + (size_t)160 * LDA, lA + 160 * 64);
        GLOAD16(gaL + (size_t)192 * LDA, lA + 192 * 64);
        GLOAD16(gaL + (size_t)224 * LDA, lA + 224 * 64);
        GLOAD16(gbgL, lB);
        GLOAD16(gbgL + (size_t)32 * LDW, lB + 32 * 64);
        GLOAD16(gbuL, lB + 64 * 64);
        GLOAD16(gbuL + (size_t)32 * LDW, lB + 96 * 64);
        __syncthreads();
#pragma unroll
        for (int s = 0; s < 2; ++s) {
            const int ao = s ? aoff1 : aoff0;
            const int bo = s ? boff1 : boff0;
            bf16x8 bv[4];
            bv[0] = *(const bf16x8*)(Bs + bo);                  // gate nj=0
            bv[1] = *(const bf16x8*)(Bs + bo + 1024);           // gate nj=1
            bv[2] = *(const bf16x8*)(Bs + bo + 64 * 64);        // up   nj=0
            bv[3] = *(const bf16x8*)(Bs + bo + 64 * 64 + 1024); // up   nj=1
#pragma unroll
            for (int g2 = 0; g2 < 2; ++g2) {
                bf16x8 av[4];
#pragma unroll
                for (int i = 0; i < 4; ++i)
                    av[i] = *(const bf16x8*)(As + ao + (g2 * 4 + i) * 1024);
#pragma unroll
                for (int i = 0; i < 4; ++i)
#pragma unroll
                    for (int j = 0; j < 4; ++j)
                        acc[g2 * 4 + i][j] = MFMA16(av[i], bv[j], acc[g2 * 4 + i][j]);
            }
        }
        __syncthreads();
        gaL += 64;
        gbgL += 64;
        gbuL += 64;
    }

#pragma unroll
    for (int mi = 0; mi < 8; ++mi)
#pragma unroll
        for (int nj = 0; nj < 2; ++nj)
#pragma unroll
            for (int rg = 0; rg < 4; ++rg) {
                int m = m0 + wr * 128 + mi * 16 + q * 4 + rg;
                int d = n0 + wc * 32 + nj * 16 + ln15;
                float g = acc[mi][nj][rg];
                float u = acc[mi][nj + 2][rg];
                float h = u * g / (1.f + __expf(-g));  // up * silu(gate)
                X2[(size_t)m * LDX2 + d] = (bf16_t)h;
            }
}

// ---------------------------------------------------------------------------
// GEMM2, 256x256 4-phase core v2 (ROUND-5 version: k-separated clusters +
// balanced reads; rest-attribution shows ~-30us vs v1).
// out = X2[8192 x 4160] @ Wdc[2048 x 4160]^T, fp32 out.
// 512 thr = 8 waves (2M x 4N), per-wave 128x64 out, acc[8][4].
// LDS 128 KiB: As0@0, As1@16384, Bs0@32768, Bs1@49152 (elements).
// Per K-tile g (buf = g&1), 4 phases:
//   p1: read aL(s0)4+bv(s0)4; stage Blo(g+1)->nxt; vmcnt(4); MFMA m0-3 k0
//   p2: read aH(s0)4;         stage Bhi(g+1)->nxt;           MFMA m4-7 k0
//   p3: read aL(s1)4+bv(s1)4; stage A1(g+1)->nxt;            MFMA m0-3 k1
//   p4: read aH(s1)4;         stage A0(g+2)->cur; vmcnt(4);  MFMA m4-7 k1
// Tail: kt clamped (harmless re-stages) so vmcnt counts stay uniform.
// ---------------------------------------------------------------------------
__global__ __launch_bounds__(512, 2) void gemm2_8p_kernel(
    const bf16_t* __restrict__ X2, const bf16_t* __restrict__ Wdc,
    float* __restrict__ out) {
    constexpr int LDA_ = 4160, LDB_ = 4160, NT_ = 65;
    constexpr int KLAST = (NT_ - 1) * 64;
    __shared__ __align__(16) bf16_t smem[65536];  // 128 KiB
    const int t = threadIdx.x;
    const int lane = t & 63, wid = t >> 6;
    const int wr = wid >> 2, wc = wid & 3;
    const int ln15 = lane & 15, q = lane >> 4;
    const int n0 = blockIdx.x * 256;
    const int m0 = blockIdx.y * 256;

    const int sw = ln15 & 7;
    const int offA0 = (wr * 128 + ln15) * 64 + ((q ^ sw) << 3);
    const int offA1 = (wr * 128 + ln15) * 64 + (((q + 4) ^ sw) << 3);
    const int offB0 = (wc * 64 + ln15) * 64 + ((q ^ sw) << 3);
    const int offB1 = (wc * 64 + ln15) * 64 + (((q + 4) ^ sw) << 3);

    const int rr = t >> 3;
    const int lch = (t & 7) ^ (rr & 7);
    const bf16_t* gA = X2 + (size_t)(m0 + rr) * LDA_ + lch * 8;
    const bf16_t* gB0 = Wdc + (size_t)(n0 + rr) * LDB_ + lch * 8;
    const bf16_t* gB2 = Wdc + (size_t)(n0 + 128 + rr) * LDB_ + lch * 8;

    f32x4 acc[8][4];
    const f32x4 z = {0.f, 0.f, 0.f, 0.f};
#pragma unroll
    for (int i = 0; i < 8; ++i)
#pragma unroll
        for (int j = 0; j < 4; ++j) acc[i][j] = z;

    auto stgA0 = [&](int kt, bf16_t* d) {  // A rows {0-63,128-191}
        GLOAD16(gA + kt, d + t * 8);
        GLOAD16(gA + (size_t)128 * LDA_ + kt, d + 128 * 64 + t * 8);
    };
    auto stgA1 = [&](int kt, bf16_t* d) {  // A rows {64-127,192-255}
        GLOAD16(gA + (size_t)64 * LDA_ + kt, d + 64 * 64 + t * 8);
        GLOAD16(gA + (size_t)192 * LDA_ + kt, d + 192 * 64 + t * 8);
    };
    auto stgBlo = [&](int kt, bf16_t* d) {  // B rows 0-127
        GLOAD16(gB0 + kt, d + t * 8);
        GLOAD16(gB0 + (size_t)64 * LDB_ + kt, d + 64 * 64 + t * 8);
    };
    auto stgBhi = [&](int kt, bf16_t* d) {  // B rows 128-255
        GLOAD16(gB2 + kt, d + 128 * 64 + t * 8);
        GLOAD16(gB2 + (size_t)64 * LDB_ + kt, d + 192 * 64 + t * 8);
    };

    bf16x8 aL[4], aH[4], bv[4];

    // Prologue: A0(0),Blo(0),Bhi(0) retired; A1(0),A0(1) in flight.
    stgA0(0, smem);
    stgBlo(0, smem + 32768);
    stgBhi(0, smem + 32768);
    stgA1(0, smem);
    stgA0(64 < KLAST ? 64 : KLAST, smem + 16384);
    VMW(4);
    BAR();

    for (int g = 0; g < NT_; ++g) {
        bf16_t* const Asc = smem + ((g & 1) << 14);
        bf16_t* const Bsc = Asc + 32768;
        bf16_t* const Asn = smem + (((g & 1) ^ 1) << 14);
        bf16_t* const Bsn = Asn + 32768;
        int k1 = (g + 1) << 6;
        if (k1 > KLAST) k1 = KLAST;
        int k2 = (g + 2) << 6;
        if (k2 > KLAST) k2 = KLAST;

        // ---- p1: m0-3 x k0 ----
#pragma unroll
        for (int i = 0; i < 4; ++i) aL[i] = *(const bf16x8*)(Asc + offA0 + i * 1024);
#pragma unroll
        for (int j = 0; j < 4; ++j) bv[j] = *(const bf16x8*)(Bsc + offB0 + j * 1024);
        stgBlo(k1, Bsn);
        VMW(4);
        PH_PRE();
        CL16(aL, bv, 0);
        PH_POST();

        // ---- p2: m4-7 x k0 ----
#pragma unroll
        for (int i = 0; i < 4; ++i) aH[i] = *(const bf16x8*)(Asc + offA0 + (4 + i) * 1024);
        stgBhi(k1, Bsn);
        PH_PRE();
        CL16(aH, bv, 4);
        PH_POST();

        // ---- p3: m0-3 x k1 ----
#pragma unroll
        for (int i = 0; i < 4; ++i) aL[i] = *(const bf16x8*)(Asc + offA1 + i * 1024);
#pragma unroll
        for (int j = 0; j < 4; ++j) bv[j] = *(const bf16x8*)(Bsc + offB1 + j * 1024);
        stgA1(k1, Asn);
        PH_PRE();
        CL16(aL, bv, 0);
        PH_POST();

        // ---- p4: m4-7 x k1 ----
#pragma unroll
        for (int i = 0; i < 4; ++i) aH[i] = *(const bf16x8*)(Asc + offA1 + (4 + i) * 1024);
        stgA0(k2, Asc);
        VMW(4);
        PH_PRE();
        CL16(aH, bv, 4);
        PH_POST();
    }
    VMW(0);

#pragma unroll
    for (int mi = 0; mi < 8; ++mi)
#pragma unroll
        for (int nj = 0; nj < 4; ++nj)
#pragma unroll
            for (int rg = 0; rg < 4; ++rg) {
                int row = wr * 128 + mi * 16 + q * 4 + rg;
                int col = wc * 64 + nj * 16 + ln15;
                out[(size_t)(m0 + row) * 2048 + (n0 + col)] = acc[mi][nj][rg];
            }
}

// ---------------------------------------------------------------------------
// Workspace layout (bytes):
//   X1   @ 0         : 8192 x 2112 bf16   [x | 0.25*x@A_gu^T]
//   W1   @ 34603008  : 8192 x 2112 bf16   [W_gu | B_gu]
//   X2   @ 69206016  : 8192 x 4160 bf16   [h | 0.25*h@A_d^T]
//   W2   @ 137363456 : 2048 x 4160 bf16   [W_d | B_d]
//   Abf  @ 154402816 : 64 x 2048 bf16
//   Adbf @ 154664960 : 64 x 4096 bf16
// ---------------------------------------------------------------------------
extern "C" void kernel_launch(void* const* d_in, const int* in_sizes, int n_in,
                              void* d_out, int out_size, void* d_ws, size_t ws_size,
                              hipStream_t stream) {
    const float* x = (const float*)d_in[0];
    const float* Wgu = (const float*)d_in[1];
    const float* Agu = (const float*)d_in[2];
    const float* Bgu = (const float*)d_in[3];
    const float* Wd = (const float*)d_in[4];
    const float* Ad = (const float*)d_in[5];
    const float* Bd = (const float*)d_in[6];
    float* out = (float*)d_out;

    char* ws = (char*)d_ws;
    bf16_t* X1 = (bf16_t*)(ws);
    bf16_t* W1 = (bf16_t*)(ws + 34603008);
    bf16_t* X2 = (bf16_t*)(ws + 69206016);
    bf16_t* W2 = (bf16_t*)(ws + 137363456);
    bf16_t* Abf = (bf16_t*)(ws + 154402816);
    bf16_t* Adbf = (bf16_t*)(ws + 154664960);

    // all fp32 -> bf16 conversions, single launch
    cvt_all_kernel<<<41984, 256, 0, stream>>>(x, Wgu, Bgu, Wd, Bd, Agu, Ad,
                                              X1, W1, W2, Abf, Adbf);

    // t1 = 0.25 * x @ A_gu^T  -> X1 cols [2048,2112)
    lora_kernel<<<128, 256, 0, stream>>>(X1, 2112, Abf, 2048, X1, 2112, 2048);
    // fused gate_up GEMM + SwiGLU -> X2 cols [0,4096)  (R4: 128x64/wave)
    gemm1_kernel<<<dim3(64, 32), 256, 0, stream>>>(X1, W1, X2);
    // t2 = 0.25 * h @ A_d^T -> X2 cols [4096,4160)
    lora_kernel<<<128, 256, 0, stream>>>(X2, 4160, Adbf, 4096, X2, 4160, 4096);
    // out = X2 @ [W_d|B_d]^T   (R5: 4-phase core v2)
    gemm2_8p_kernel<<<dim3(8, 32), 512, 0, stream>>>(X2, W2, out);
}

// Round 8
// 615.117 us; speedup vs baseline: 1.0158x; 1.0112x over previous
//
#include <hip/hip_runtime.h>
#include <stdint.h>

typedef __bf16 bf16_t;
typedef __bf16 bf16x8 __attribute__((ext_vector_type(8)));
typedef __bf16 bf16x4 __attribute__((ext_vector_type(4)));
typedef float f32x4 __attribute__((ext_vector_type(4)));

// Async global->LDS, 16B per lane (wave-uniform base + lane*16).
#define GLOAD16(gp, lp)                                                        \
    __builtin_amdgcn_global_load_lds(                                          \
        (const __attribute__((address_space(1))) void*)(gp),                   \
        (__attribute__((address_space(3))) void*)(lp), 16, 0, 0)

#define MFMA16(a, b, c) __builtin_amdgcn_mfma_f32_16x16x32_bf16(a, b, c, 0, 0, 0)

#define BAR() asm volatile("s_barrier" ::: "memory")
#define LGKM0() asm volatile("s_waitcnt lgkmcnt(0)" ::: "memory")
#define VMW(n) asm volatile("s_waitcnt vmcnt(" #n ")" ::: "memory")

// BK=64 LDS tiles: row = 64 bf16 = 128 B = 32 banks; chunk c of row r lives
// in slot c ^ (r&7) (pre-swizzled global source, linear LDS dest). Readers
// XOR the same way -> 2-way (free) on ds_read_b128.

// ---------------------------------------------------------------------------
// All fp32 -> bf16 conversions in ONE launch (7 segments).
// ---------------------------------------------------------------------------
__global__ __launch_bounds__(256) void cvt_all_kernel(
    const float* __restrict__ x, const float* __restrict__ Wgu,
    const float* __restrict__ Bgu, const float* __restrict__ Wd,
    const float* __restrict__ Bd, const float* __restrict__ Agu,
    const float* __restrict__ Ad, bf16_t* __restrict__ X1,
    bf16_t* __restrict__ W1, bf16_t* __restrict__ W2,
    bf16_t* __restrict__ Abf, bf16_t* __restrict__ Adbf) {
    int b = blockIdx.x;
    const float* src;
    bf16_t* dst;
    int cshift, cmask, ldd, coff, lb;
    if (b < 16384) {
        src = x; dst = X1; cshift = 11; cmask = 2047; ldd = 2112; coff = 0; lb = b;
    } else if (b < 32768) {
        src = Wgu; dst = W1; cshift = 11; cmask = 2047; ldd = 2112; coff = 0; lb = b - 16384;
    } else if (b < 33280) {
        src = Bgu; dst = W1; cshift = 6; cmask = 63; ldd = 2112; coff = 2048; lb = b - 32768;
    } else if (b < 41472) {
        src = Wd; dst = W2; cshift = 12; cmask = 4095; ldd = 4160; coff = 0; lb = b - 33280;
    } else if (b < 41600) {
        src = Bd; dst = W2; cshift = 6; cmask = 63; ldd = 4160; coff = 4096; lb = b - 41472;
    } else if (b < 41728) {
        src = Agu; dst = Abf; cshift = 11; cmask = 2047; ldd = 2048; coff = 0; lb = b - 41600;
    } else {
        src = Ad; dst = Adbf; cshift = 12; cmask = 4095; ldd = 4096; coff = 0; lb = b - 41728;
    }
    int idx = (lb * 256 + threadIdx.x) << 2;
    int r = idx >> cshift;
    int c = idx & cmask;
    float4 v = *(const float4*)(src + idx);
    bf16x4 o = {(bf16_t)v.x, (bf16_t)v.y, (bf16_t)v.z, (bf16_t)v.w};
    *(bf16x4*)(dst + (size_t)r * ldd + coff + c) = o;
}

// ---------------------------------------------------------------------------
// LoRA GEMM v2 (double-buffered): t = 0.25 * (A[M x K] @ Bw[64 x K]^T).
// Old version did GLOAD -> __syncthreads (= vmcnt(0) drain) per K-iter: a
// full memory-latency round trip x 32/64 serial iters, latency-bound.
// Now: stage(g+1) issued BEFORE the tile-g gate; vmcnt(4) keeps the new
// tile's 4 loads in flight; trailing lgkm0+barrier guarantees all waves'
// reads of a buffer complete before it is re-staged (>=1 barrier later).
// LDS 2 x (A 64x64 + B 64x64) = 32 KB.
// ---------------------------------------------------------------------------
__global__ __launch_bounds__(256) void lora_kernel(const bf16_t* __restrict__ A,
                                                   int lda,
                                                   const bf16_t* __restrict__ Bw,
                                                   int K, bf16_t* __restrict__ dst,
                                                   int ldd, int coff) {
    __shared__ __align__(16) bf16_t As[2 * 64 * 64];
    __shared__ __align__(16) bf16_t Bs[2 * 64 * 64];
    const int t = threadIdx.x;
    const int m0 = blockIdx.x * 64;
    const int lane = t & 63, w = t >> 6;
    const int ln15 = lane & 15, q = lane >> 4;

    const int lrow = t >> 3;
    const int lchunk = (t & 7) ^ (lrow & 7);
    const bf16_t* gaL = A + (size_t)(m0 + lrow) * lda + lchunk * 8;
    const bf16_t* gbL = Bw + (size_t)lrow * K + lchunk * 8;

    const f32x4 z = {0.f, 0.f, 0.f, 0.f};
    f32x4 acc[4];
#pragma unroll
    for (int j = 0; j < 4; ++j) acc[j] = z;

    int aoffs[2], boffs[2][4];
#pragma unroll
    for (int s = 0; s < 2; ++s) {
        int rowa = w * 16 + ln15;
        aoffs[s] = rowa * 64 + (((q + 4 * s) ^ (rowa & 7)) << 3);
#pragma unroll
        for (int j = 0; j < 4; ++j) {
            int rowb = j * 16 + ln15;
            boffs[s][j] = rowb * 64 + (((q + 4 * s) ^ (rowb & 7)) << 3);
        }
    }

    auto stage = [&](int kt, int bo) {
        GLOAD16(gaL + kt, As + bo + t * 8);
        GLOAD16(gaL + kt + (size_t)32 * lda, As + bo + 2048 + t * 8);
        GLOAD16(gbL + kt, Bs + bo + t * 8);
        GLOAD16(gbL + kt + (size_t)32 * K, Bs + bo + 2048 + t * 8);
    };

    const int NT = K >> 6;
    stage(0, 0);
    for (int g = 0; g < NT; ++g) {
        const bool more = (g + 1) < NT;
        if (more) stage((g + 1) << 6, ((g + 1) & 1) * 4096);
        if (more)
            VMW(4);  // retire tile g's 4 loads; keep tile g+1's in flight
        else
            VMW(0);
        BAR();
        const int bo = (g & 1) * 4096;
#pragma unroll
        for (int s = 0; s < 2; ++s) {
            bf16x8 av = *(const bf16x8*)(As + bo + aoffs[s]);
#pragma unroll
            for (int j = 0; j < 4; ++j) {
                bf16x8 bv = *(const bf16x8*)(Bs + bo + boffs[s][j]);
                acc[j] = MFMA16(av, bv, acc[j]);
            }
        }
        LGKM0();  // this wave's reads of buf done (in-order DS) ...
        BAR();    // ... all waves done -> safe to re-stage this buf next iter
    }

#pragma unroll
    for (int j = 0; j < 4; ++j)
#pragma unroll
        for (int rg = 0; rg < 4; ++rg) {
            int m = m0 + w * 16 + q * 4 + rg;
            dst[(size_t)m * ldd + coff + j * 16 + ln15] = (bf16_t)(acc[j][rg] * 0.25f);
        }
}

// ---------------------------------------------------------------------------
// GEMM1 (ROUND-4 version, best measured 247 us, MfmaUtil 54%):
// per-wave tile 128x64. Block: 256 thr = 4 waves (2M x 2N). Tile M=256,
// out-cols 64 (gate+up). acc[8][4] (nj 0-1 gate, 2-3 up); SwiGLU in-register.
// LDS: A 256x64 + B 128x64 = 48 KB -> 2 blk/CU. Plain 2-barrier loop.
// ---------------------------------------------------------------------------
__global__ __launch_bounds__(256, 2) void gemm1_kernel(const bf16_t* __restrict__ X,
                                                       const bf16_t* __restrict__ Wc,
                                                       bf16_t* __restrict__ X2) {
    constexpr int LDA = 2112, LDW = 2112, LDX2 = 4160, K = 2112;
    __shared__ __align__(16) bf16_t As[256 * 64];  // 32 KB
    __shared__ __align__(16) bf16_t Bs[128 * 64];  // 16 KB
    const int t = threadIdx.x;
    const int n0 = blockIdx.x * 64;
    const int m0 = blockIdx.y * 256;
    const int lane = t & 63, w = t >> 6, wr = w >> 1, wc = w & 1;
    const int ln15 = lane & 15, q = lane >> 4;

    const int lrow = t >> 3;
    const int lchunk = (t & 7) ^ (lrow & 7);
    const bf16_t* gaL = X + (size_t)(m0 + lrow) * LDA + lchunk * 8;
    const bf16_t* gbgL = Wc + (size_t)(n0 + lrow) * LDW + lchunk * 8;          // gate
    const bf16_t* gbuL = Wc + (size_t)(4096 + n0 + lrow) * LDW + lchunk * 8;   // up
    bf16_t* lA = As + t * 8;
    bf16_t* lB = Bs + t * 8;

    const f32x4 z = {0.f, 0.f, 0.f, 0.f};
    f32x4 acc[8][4];  // [mi][nj]: nj 0-1 gate, 2-3 up
#pragma unroll
    for (int i = 0; i < 8; ++i)
#pragma unroll
        for (int j = 0; j < 4; ++j) acc[i][j] = z;

    // row&7 == ln15&7 for every fragment (frag strides are multiples of 16),
    // so each s-half needs only one base offset; frag steps are +1024.
    const int sw7 = ln15 & 7;
    const int arow = wr * 128 + ln15;
    const int aoff0 = arow * 64 + ((q ^ sw7) << 3);
    const int aoff1 = arow * 64 + (((q + 4) ^ sw7) << 3);
    const int brow = wc * 32 + ln15;
    const int boff0 = brow * 64 + ((q ^ sw7) << 3);
    const int boff1 = brow * 64 + (((q + 4) ^ sw7) << 3);

    for (int kt = 0; kt < K; kt += 64) {
        GLOAD16(gaL, lA);
        GLOAD16(gaL + (size_t)32 * LDA, lA + 32 * 64);
        GLOAD16(gaL + (size_t)64 * LDA, lA + 64 * 64);
        GLOAD16(gaL + (size_t)96 * LDA, lA + 96 * 64);
        GLOAD16(gaL + (size_t)128 * LDA, lA + 128 * 64);
        GLOAD16(gaL + (size_t)160 * LDA, lA + 160 * 64);
        GLOAD16(gaL + (size_t)192 * LDA, lA + 192 * 64);
        GLOAD16(gaL + (size_t)224 * LDA, lA + 224 * 64);
        GLOAD16(gbgL, lB);
        GLOAD16(gbgL + (size_t)32 * LDW, lB + 32 * 64);
        GLOAD16(gbuL, lB + 64 * 64);
        GLOAD16(gbuL + (size_t)32 * LDW, lB + 96 * 64);
        __syncthreads();
#pragma unroll
        for (int s = 0; s < 2; ++s) {
            const int ao = s ? aoff1 : aoff0;
            const int bo = s ? boff1 : boff0;
            bf16x8 bv[4];
            bv[0] = *(const bf16x8*)(Bs + bo);                  // gate nj=0
            bv[1] = *(const bf16x8*)(Bs + bo + 1024);           // gate nj=1
            bv[2] = *(const bf16x8*)(Bs + bo + 64 * 64);        // up   nj=0
            bv[3] = *(const bf16x8*)(Bs + bo + 64 * 64 + 1024); // up   nj=1
#pragma unroll
            for (int g2 = 0; g2 < 2; ++g2) {
                bf16x8 av[4];
#pragma unroll
                for (int i = 0; i < 4; ++i)
                    av[i] = *(const bf16x8*)(As + ao + (g2 * 4 + i) * 1024);
#pragma unroll
                for (int i = 0; i < 4; ++i)
#pragma unroll
                    for (int j = 0; j < 4; ++j)
                        acc[g2 * 4 + i][j] = MFMA16(av[i], bv[j], acc[g2 * 4 + i][j]);
            }
        }
        __syncthreads();
        gaL += 64;
        gbgL += 64;
        gbuL += 64;
    }

#pragma unroll
    for (int mi = 0; mi < 8; ++mi)
#pragma unroll
        for (int nj = 0; nj < 2; ++nj)
#pragma unroll
            for (int rg = 0; rg < 4; ++rg) {
                int m = m0 + wr * 128 + mi * 16 + q * 4 + rg;
                int d = n0 + wc * 32 + nj * 16 + ln15;
                float g = acc[mi][nj][rg];
                float u = acc[mi][nj + 2][rg];
                float h = u * g / (1.f + __expf(-g));  // up * silu(gate)
                X2[(size_t)m * LDX2 + d] = (bf16_t)h;
            }
}

// ---------------------------------------------------------------------------
// GEMM2 v3: mirror of the measured-best 2-barrier structure (54% MfmaUtil
// on gemm1 vs 44% for every phase-barrier variant on this problem).
// out = X2[8192 x 4160] @ Wdc[2048 x 4160]^T, fp32 out.
// Block: 256 thr = 4 waves (2M x 2N), tile 256m x 128n, per-wave 128x64.
// LDS: A 256x64 + B 128x64 = 48 KB -> 2 blk/CU; grid (16,32) = 512 blocks
// = exactly 2 rounds; cross-block TLP covers the barrier drain.
// ---------------------------------------------------------------------------
__global__ __launch_bounds__(256, 2) void gemm2_kernel(const bf16_t* __restrict__ X2,
                                                       const bf16_t* __restrict__ Wdc,
                                                       float* __restrict__ out) {
    constexpr int LDA = 4160, LDB = 4160, K = 4160, LDO = 2048;
    __shared__ __align__(16) bf16_t As[256 * 64];  // 32 KB
    __shared__ __align__(16) bf16_t Bs[128 * 64];  // 16 KB
    const int t = threadIdx.x;
    const int n0 = blockIdx.x * 128;
    const int m0 = blockIdx.y * 256;
    const int lane = t & 63, w = t >> 6, wr = w >> 1, wc = w & 1;
    const int ln15 = lane & 15, q = lane >> 4;

    const int lrow = t >> 3;
    const int lchunk = (t & 7) ^ (lrow & 7);
    const bf16_t* gaL = X2 + (size_t)(m0 + lrow) * LDA + lchunk * 8;
    const bf16_t* gbL = Wdc + (size_t)(n0 + lrow) * LDB + lchunk * 8;
    bf16_t* lA = As + t * 8;
    bf16_t* lB = Bs + t * 8;

    const f32x4 z = {0.f, 0.f, 0.f, 0.f};
    f32x4 acc[8][4];
#pragma unroll
    for (int i = 0; i < 8; ++i)
#pragma unroll
        for (int j = 0; j < 4; ++j) acc[i][j] = z;

    const int sw7 = ln15 & 7;
    const int arow = wr * 128 + ln15;
    const int aoff0 = arow * 64 + ((q ^ sw7) << 3);
    const int aoff1 = arow * 64 + (((q + 4) ^ sw7) << 3);
    const int brow = wc * 64 + ln15;
    const int boff0 = brow * 64 + ((q ^ sw7) << 3);
    const int boff1 = brow * 64 + (((q + 4) ^ sw7) << 3);

    for (int kt = 0; kt < K; kt += 64) {
        GLOAD16(gaL, lA);
        GLOAD16(gaL + (size_t)32 * LDA, lA + 32 * 64);
        GLOAD16(gaL + (size_t)64 * LDA, lA + 64 * 64);
        GLOAD16(gaL + (size_t)96 * LDA, lA + 96 * 64);
        GLOAD16(gaL + (size_t)128 * LDA, lA + 128 * 64);
        GLOAD16(gaL + (size_t)160 * LDA, lA + 160 * 64);
        GLOAD16(gaL + (size_t)192 * LDA, lA + 192 * 64);
        GLOAD16(gaL + (size_t)224 * LDA, lA + 224 * 64);
        GLOAD16(gbL, lB);
        GLOAD16(gbL + (size_t)32 * LDB, lB + 32 * 64);
        GLOAD16(gbL + (size_t)64 * LDB, lB + 64 * 64);
        GLOAD16(gbL + (size_t)96 * LDB, lB + 96 * 64);
        __syncthreads();
#pragma unroll
        for (int s = 0; s < 2; ++s) {
            const int ao = s ? aoff1 : aoff0;
            const int bo = s ? boff1 : boff0;
            bf16x8 bv[4];
#pragma unroll
            for (int j = 0; j < 4; ++j)
                bv[j] = *(const bf16x8*)(Bs + bo + j * 1024);
#pragma unroll
            for (int g2 = 0; g2 < 2; ++g2) {
                bf16x8 av[4];
#pragma unroll
                for (int i = 0; i < 4; ++i)
                    av[i] = *(const bf16x8*)(As + ao + (g2 * 4 + i) * 1024);
#pragma unroll
                for (int i = 0; i < 4; ++i)
#pragma unroll
                    for (int j = 0; j < 4; ++j)
                        acc[g2 * 4 + i][j] = MFMA16(av[i], bv[j], acc[g2 * 4 + i][j]);
            }
        }
        __syncthreads();
        gaL += 64;
        gbL += 64;
    }

#pragma unroll
    for (int mi = 0; mi < 8; ++mi)
#pragma unroll
        for (int nj = 0; nj < 4; ++nj)
#pragma unroll
            for (int rg = 0; rg < 4; ++rg) {
                int m = m0 + wr * 128 + mi * 16 + q * 4 + rg;
                int n = n0 + wc * 64 + nj * 16 + ln15;
                out[(size_t)m * LDO + n] = acc[mi][nj][rg];
            }
}

// ---------------------------------------------------------------------------
// Workspace layout (bytes):
//   X1   @ 0         : 8192 x 2112 bf16   [x | 0.25*x@A_gu^T]
//   W1   @ 34603008  : 8192 x 2112 bf16   [W_gu | B_gu]
//   X2   @ 69206016  : 8192 x 4160 bf16   [h | 0.25*h@A_d^T]
//   W2   @ 137363456 : 2048 x 4160 bf16   [W_d | B_d]
//   Abf  @ 154402816 : 64 x 2048 bf16
//   Adbf @ 154664960 : 64 x 4096 bf16
// ---------------------------------------------------------------------------
extern "C" void kernel_launch(void* const* d_in, const int* in_sizes, int n_in,
                              void* d_out, int out_size, void* d_ws, size_t ws_size,
                              hipStream_t stream) {
    const float* x = (const float*)d_in[0];
    const float* Wgu = (const float*)d_in[1];
    const float* Agu = (const float*)d_in[2];
    const float* Bgu = (const float*)d_in[3];
    const float* Wd = (const float*)d_in[4];
    const float* Ad = (const float*)d_in[5];
    const float* Bd = (const float*)d_in[6];
    float* out = (float*)d_out;

    char* ws = (char*)d_ws;
    bf16_t* X1 = (bf16_t*)(ws);
    bf16_t* W1 = (bf16_t*)(ws + 34603008);
    bf16_t* X2 = (bf16_t*)(ws + 69206016);
    bf16_t* W2 = (bf16_t*)(ws + 137363456);
    bf16_t* Abf = (bf16_t*)(ws + 154402816);
    bf16_t* Adbf = (bf16_t*)(ws + 154664960);

    // all fp32 -> bf16 conversions, single launch
    cvt_all_kernel<<<41984, 256, 0, stream>>>(x, Wgu, Bgu, Wd, Bd, Agu, Ad,
                                              X1, W1, W2, Abf, Adbf);

    // t1 = 0.25 * x @ A_gu^T  -> X1 cols [2048,2112)   (dbuf lora)
    lora_kernel<<<128, 256, 0, stream>>>(X1, 2112, Abf, 2048, X1, 2112, 2048);
    // fused gate_up GEMM + SwiGLU -> X2 cols [0,4096)  (R4: 128x64/wave)
    gemm1_kernel<<<dim3(64, 32), 256, 0, stream>>>(X1, W1, X2);
    // t2 = 0.25 * h @ A_d^T -> X2 cols [4096,4160)     (dbuf lora)
    lora_kernel<<<128, 256, 0, stream>>>(X2, 4160, Adbf, 4096, X2, 4160, 4096);
    // out = X2 @ [W_d|B_d]^T   (v3: 2-barrier 256x128, 2 blk/CU)
    gemm2_kernel<<<dim3(16, 32), 256, 0, stream>>>(X2, W2, out);
}